// Round 10
// baseline (114.360 us; speedup 1.0000x reference)
//
#include <hip/hip_runtime.h>
#include <hip/hip_fp16.h>

#define D 64

// byte k of u -> float (v_cvt_f32_ubyte_k)
__device__ __forceinline__ float ub0(unsigned u) {
#if __has_builtin(__builtin_amdgcn_cvt_f32_ubyte0)
    return __builtin_amdgcn_cvt_f32_ubyte0(u);
#else
    return (float)(u & 0xFF);
#endif
}
__device__ __forceinline__ float ub1(unsigned u) {
#if __has_builtin(__builtin_amdgcn_cvt_f32_ubyte1)
    return __builtin_amdgcn_cvt_f32_ubyte1(u);
#else
    return (float)((u >> 8) & 0xFF);
#endif
}
__device__ __forceinline__ float ub2(unsigned u) {
#if __has_builtin(__builtin_amdgcn_cvt_f32_ubyte2)
    return __builtin_amdgcn_cvt_f32_ubyte2(u);
#else
    return (float)((u >> 16) & 0xFF);
#endif
}
__device__ __forceinline__ float ub3(unsigned u) {
#if __has_builtin(__builtin_amdgcn_cvt_f32_ubyte3)
    return __builtin_amdgcn_cvt_f32_ubyte3(u);
#else
    return (float)(u >> 24);
#endif
}

// ---------------------------------------------------------------------------
// Kernel 1 (merged): blocks [0, gemmBlocks): Xp16 = f16(X @ W), plus an int8
// per-row-scaled copy Q (biased: q+128) and per-row scale (rowmax/127).
// Blocks [gemmBlocks, ...): CSR rowptr from sorted `row`.
// ---------------------------------------------------------------------------
__global__ __launch_bounds__(256) void prep_kernel(const float* __restrict__ X,
                                                   const float* __restrict__ W,
                                                   const int* __restrict__ row,
                                                   __half* __restrict__ Xp16,
                                                   unsigned char* __restrict__ Q,
                                                   float* __restrict__ scales,
                                                   int* __restrict__ rowptr,
                                                   int nNodes, int nEdges,
                                                   int gemmBlocks) {
    if ((int)blockIdx.x >= gemmBlocks) {
        int e = (blockIdx.x - gemmBlocks) * 256 + threadIdx.x;
        if (e >= nEdges) return;
        int r = row[e];
        int rprev = (e == 0) ? -1 : row[e - 1];
        for (int q = rprev + 1; q <= r; ++q) rowptr[q] = e;
        if (e == nEdges - 1) {
            for (int q = r + 1; q <= nNodes; ++q) rowptr[q] = nEdges;
        }
        return;
    }
    int lane = threadIdx.x & 63;
    int wave = (blockIdx.x * 256 + threadIdx.x) >> 6;
    int nWaves = gemmBlocks * 4;

    float w[D];
#pragma unroll
    for (int k = 0; k < D; ++k) w[k] = W[k * D + lane];

    for (int r = wave; r < nNodes; r += nWaves) {
        int rr = __builtin_amdgcn_readfirstlane(r);
        const float4* xr = (const float4*)(X + (size_t)rr * D);
        float acc = 0.f;
#pragma unroll
        for (int k4 = 0; k4 < D / 4; ++k4) {
            float4 xv = xr[k4];
            acc = fmaf(xv.x, w[4 * k4 + 0], acc);
            acc = fmaf(xv.y, w[4 * k4 + 1], acc);
            acc = fmaf(xv.z, w[4 * k4 + 2], acc);
            acc = fmaf(xv.w, w[4 * k4 + 3], acc);
        }
        Xp16[(size_t)rr * D + lane] = __float2half(acc);

        // per-row absmax across the 64 lanes (butterfly max)
        float m = fabsf(acc);
#pragma unroll
        for (int off = 1; off < 64; off <<= 1)
            m = fmaxf(m, __shfl_xor(m, off, 64));

        float inv   = (m > 0.f) ? 127.f / m : 0.f;
        float scale = (m > 0.f) ? m / 127.f : 0.f;
        int q = (int)rintf(acc * inv);
        q = q < -127 ? -127 : (q > 127 ? 127 : q);
        Q[(size_t)rr * D + lane] = (unsigned char)(q + 128);
        if (lane == 0) scales[rr] = scale;
    }
}

// ---------------------------------------------------------------------------
// Kernel 2: fused SDDMM + SpMM. Static wave->octet map. One 8-lane group per
// node (8 nodes/wave); lane j holds dims 8j..8j+7. Gathered SRC rows are
// int8 biased (uint2/lane -> ONE 64B line per edge; 3.2MB table L2-resident).
// Bias/scale algebra is folded out of the inner loop:
//   y_q = scale*(c_q - 128)
//   dot:  p  = scale*(sum xr*c - 128*SX),  SX = sum_q xr[q]  (per node)
//   acc:  acc[q] += ss*c_q,  ss = attn*p*scale;  correction -128*sum(ss)
// applied once in the epilogue. All f32 accumulation. No output atomics.
// ---------------------------------------------------------------------------
__global__ __launch_bounds__(256) void fused_kernel(const __half* __restrict__ Xp16,
                                                    const unsigned char* __restrict__ Q,
                                                    const float* __restrict__ scales,
                                                    const int* __restrict__ rowptr,
                                                    const int* __restrict__ col,
                                                    const float* __restrict__ attn_w,
                                                    float* __restrict__ out,
                                                    int nNodes) {
    int lane = threadIdx.x & 63;
    int waveId = (blockIdx.x * 256 + threadIdx.x) >> 6;
    int g = lane >> 3;        // node slot within wave
    int j = lane & 7;         // dim chunk: dims 8j..8j+7

    int node = waveId * 8 + g;
    bool active = node < nNodes;
    int nd = active ? node : 0;

    int eStart = rowptr[nd];
    int eEnd   = active ? rowptr[nd + 1] : eStart;

    // dst row chunk: f16 -> f32, once per node
    const uint4* Xp16V = (const uint4*)Xp16;
    uint4 xru = Xp16V[(size_t)nd * 8 + j];
    float xrf[8];
    {
        float2 t;
        t = __half22float2(*(const __half2*)&xru.x); xrf[0] = t.x; xrf[1] = t.y;
        t = __half22float2(*(const __half2*)&xru.y); xrf[2] = t.x; xrf[3] = t.y;
        t = __half22float2(*(const __half2*)&xru.z); xrf[4] = t.x; xrf[5] = t.y;
        t = __half22float2(*(const __half2*)&xru.w); xrf[6] = t.x; xrf[7] = t.y;
    }
    // SX128 = 128 * (full 64-dim sum of xr)
    float sx = 0.f;
#pragma unroll
    for (int q = 0; q < 8; ++q) sx += xrf[q];
#pragma unroll
    for (int off = 1; off < 8; off <<= 1) sx += __shfl_xor(sx, off, 64);
    float SX128 = 128.f * sx;

    const uint2* QV = (const uint2*)Q;                // row stride = 8 uint2 (64 B)

    float acc[8] = {0.f, 0.f, 0.f, 0.f, 0.f, 0.f, 0.f, 0.f};
    float SS = 0.f;                                   // sum of ss_e (bias correction)

    // prologue: batch 0 (safe index 0 for out-of-range slots)
    bool v[8]; uint2 raw[8]; float sc[8];
#pragma unroll
    for (int u = 0; u < 8; ++u) {
        int ee = eStart + u;
        v[u] = ee < eEnd;
        int cc = col[v[u] ? ee : 0];
        raw[u] = QV[(size_t)cc * 8 + j];
        sc[u]  = scales[cc];
    }

    for (int e = eStart; e < eEnd; e += 8) {
        // ---- issue batch i+1 loads first ----
        bool v2[8]; uint2 raw2[8]; float sc2[8];
#pragma unroll
        for (int u = 0; u < 8; ++u) {
            int ee = e + 8 + u;
            v2[u] = ee < eEnd;
            int cc = col[v2[u] ? ee : 0];
            raw2[u] = QV[(size_t)cc * 8 + j];
            sc2[u]  = scales[cc];
        }
        // ---- consume batch i ----
        float d[8];
#pragma unroll
        for (int u = 0; u < 8; ++u) {
            unsigned a = raw[u].x, b = raw[u].y;
            float s = 0.f;
            s = fmaf(xrf[0], ub0(a), s); s = fmaf(xrf[1], ub1(a), s);
            s = fmaf(xrf[2], ub2(a), s); s = fmaf(xrf[3], ub3(a), s);
            s = fmaf(xrf[4], ub0(b), s); s = fmaf(xrf[5], ub1(b), s);
            s = fmaf(xrf[6], ub2(b), s); s = fmaf(xrf[7], ub3(b), s);
            d[u] = s;
        }
#pragma unroll
        for (int off = 1; off < 8; off <<= 1)
#pragma unroll
            for (int u = 0; u < 8; ++u) d[u] += __shfl_xor(d[u], off, 64);
#pragma unroll
        for (int u = 0; u < 8; ++u) {
            float p  = sc[u] * (d[u] - SX128);        // un-attn'd edge score
            float ss = v[u] ? p * sc[u] : 0.f;        // attn deferred to epilogue
            SS += ss;
            unsigned a = raw[u].x, b = raw[u].y;
            acc[0] = fmaf(ss, ub0(a), acc[0]); acc[1] = fmaf(ss, ub1(a), acc[1]);
            acc[2] = fmaf(ss, ub2(a), acc[2]); acc[3] = fmaf(ss, ub3(a), acc[3]);
            acc[4] = fmaf(ss, ub0(b), acc[4]); acc[5] = fmaf(ss, ub1(b), acc[5]);
            acc[6] = fmaf(ss, ub2(b), acc[6]); acc[7] = fmaf(ss, ub3(b), acc[7]);
        }
        // ---- rotate ----
#pragma unroll
        for (int u = 0; u < 8; ++u) { v[u] = v2[u]; raw[u] = raw2[u]; sc[u] = sc2[u]; }
    }

    if (active) {
        float attn = attn_w[0];
        float corr = 128.f * SS;                      // bias term, dim-independent
        float4* o = (float4*)(out + (size_t)node * D + 8 * j);
        o[0] = make_float4(attn * (acc[0] - corr), attn * (acc[1] - corr),
                           attn * (acc[2] - corr), attn * (acc[3] - corr));
        o[1] = make_float4(attn * (acc[4] - corr), attn * (acc[5] - corr),
                           attn * (acc[6] - corr), attn * (acc[7] - corr));
    }
}

extern "C" void kernel_launch(void* const* d_in, const int* in_sizes, int n_in,
                              void* d_out, int out_size, void* d_ws, size_t ws_size,
                              hipStream_t stream) {
    const float* X    = (const float*)d_in[0];
    const float* W    = (const float*)d_in[1];
    const float* attn = (const float*)d_in[2];
    const int*   row  = (const int*)d_in[3];
    const int*   col  = (const int*)d_in[4];
    float* out = (float*)d_out;

    int nNodes = in_sizes[0] / D;
    int nEdges = in_sizes[3];

    // workspace: Q [nNodes*64 B] | scales [nNodes f32] | Xp16 [nNodes*128 B] | rowptr
    unsigned char* Q = (unsigned char*)d_ws;
    float* scales = (float*)(Q + (size_t)nNodes * D);
    __half* Xp16  = (__half*)(scales + nNodes);
    int* rowptr   = (int*)((char*)Xp16 + (size_t)nNodes * D * sizeof(__half));

    int gemmBlocks = 1024;
    int rpBlocks   = (nEdges + 255) / 256;
    prep_kernel<<<gemmBlocks + rpBlocks, 256, 0, stream>>>(X, W, row, Xp16, Q, scales,
                                                           rowptr, nNodes, nEdges,
                                                           gemmBlocks);

    int waves = (nNodes + 7) / 8;                        // 8 nodes per wave
    fused_kernel<<<(waves + 3) / 4, 256, 0, stream>>>(Xp16, Q, scales, rowptr, col,
                                                      attn, out, nNodes);
}

// Round 11
// 105.693 us; speedup vs baseline: 1.0820x; 1.0820x over previous
//
#include <hip/hip_runtime.h>
#include <hip/hip_fp16.h>

#define D 64

typedef _Float16 h16;
typedef h16 h16x2 __attribute__((ext_vector_type(2)));

__device__ __forceinline__ h16x2 u2h(unsigned int u) {
    union { unsigned int i; h16x2 h; } t; t.i = u; return t.h;
}

// dot of 8 f16 pairs (two uint4-packed rows), f32 accumulate
__device__ __forceinline__ float dot8_f16(uint4 a, uint4 b, float c) {
#if __has_builtin(__builtin_amdgcn_fdot2)
    c = __builtin_amdgcn_fdot2(u2h(a.x), u2h(b.x), c, false);
    c = __builtin_amdgcn_fdot2(u2h(a.y), u2h(b.y), c, false);
    c = __builtin_amdgcn_fdot2(u2h(a.z), u2h(b.z), c, false);
    c = __builtin_amdgcn_fdot2(u2h(a.w), u2h(b.w), c, false);
    return c;
#else
    float2 t, s;
    t = __half22float2(*(const __half2*)&a.x); s = __half22float2(*(const __half2*)&b.x);
    c = fmaf(t.x, s.x, c); c = fmaf(t.y, s.y, c);
    t = __half22float2(*(const __half2*)&a.y); s = __half22float2(*(const __half2*)&b.y);
    c = fmaf(t.x, s.x, c); c = fmaf(t.y, s.y, c);
    t = __half22float2(*(const __half2*)&a.z); s = __half22float2(*(const __half2*)&b.z);
    c = fmaf(t.x, s.x, c); c = fmaf(t.y, s.y, c);
    t = __half22float2(*(const __half2*)&a.w); s = __half22float2(*(const __half2*)&b.w);
    c = fmaf(t.x, s.x, c); c = fmaf(t.y, s.y, c);
    return c;
#endif
}

__device__ __forceinline__ void h8_to_f32(uint4 u, float f[8]) {
    float2 t;
    t = __half22float2(*(const __half2*)&u.x); f[0] = t.x; f[1] = t.y;
    t = __half22float2(*(const __half2*)&u.y); f[2] = t.x; f[3] = t.y;
    t = __half22float2(*(const __half2*)&u.z); f[4] = t.x; f[5] = t.y;
    t = __half22float2(*(const __half2*)&u.w); f[6] = t.x; f[7] = t.y;
}

// ---------------------------------------------------------------------------
// Kernel 1 (merged): blocks [0, gemmBlocks) compute Xp = f16(X @ W);
// blocks [gemmBlocks, ...) build CSR rowptr from sorted `row`.
// ---------------------------------------------------------------------------
__global__ __launch_bounds__(256) void prep_kernel(const float* __restrict__ X,
                                                   const float* __restrict__ W,
                                                   const int* __restrict__ row,
                                                   __half* __restrict__ Xp,
                                                   int* __restrict__ rowptr,
                                                   int nNodes, int nEdges,
                                                   int gemmBlocks) {
    if ((int)blockIdx.x >= gemmBlocks) {
        int e = (blockIdx.x - gemmBlocks) * 256 + threadIdx.x;
        if (e >= nEdges) return;
        int r = row[e];
        int rprev = (e == 0) ? -1 : row[e - 1];
        for (int q = rprev + 1; q <= r; ++q) rowptr[q] = e;
        if (e == nEdges - 1) {
            for (int q = r + 1; q <= nNodes; ++q) rowptr[q] = nEdges;
        }
        return;
    }
    int lane = threadIdx.x & 63;
    int wave = (blockIdx.x * 256 + threadIdx.x) >> 6;
    int nWaves = gemmBlocks * 4;

    float w[D];
#pragma unroll
    for (int k = 0; k < D; ++k) w[k] = W[k * D + lane];

    for (int r = wave; r < nNodes; r += nWaves) {
        int rr = __builtin_amdgcn_readfirstlane(r);
        const float4* xr = (const float4*)(X + (size_t)rr * D);
        float acc = 0.f;
#pragma unroll
        for (int k4 = 0; k4 < D / 4; ++k4) {
            float4 xv = xr[k4];
            acc = fmaf(xv.x, w[4 * k4 + 0], acc);
            acc = fmaf(xv.y, w[4 * k4 + 1], acc);
            acc = fmaf(xv.z, w[4 * k4 + 2], acc);
            acc = fmaf(xv.w, w[4 * k4 + 3], acc);
        }
        Xp[(size_t)rr * D + lane] = __float2half(acc);
    }
}

// ---------------------------------------------------------------------------
// Kernel 2: fused SDDMM + SpMM (best-measured config, round 6).
// Static wave->octet map; one 8-lane group per node (8 nodes/wave); lane j
// holds dims 8j..8j+7 (uint4 of f16). 4-edge batches, double-buffered:
// batch i+1's col loads + gathers issue before batch i is consumed.
// Dot = 4 x v_dot2_f32_f16 + 3-shfl in-group reduce; f32 accumulators.
// attn applied once in the epilogue. Coalesced stores, no atomics.
// ---------------------------------------------------------------------------
__global__ __launch_bounds__(256) void fused_kernel(const __half* __restrict__ Xp,
                                                    const int* __restrict__ rowptr,
                                                    const int* __restrict__ col,
                                                    const float* __restrict__ attn_w,
                                                    float* __restrict__ out,
                                                    int nNodes) {
    int lane = threadIdx.x & 63;
    int waveId = (blockIdx.x * 256 + threadIdx.x) >> 6;
    int g = lane >> 3;        // node slot within wave
    int j = lane & 7;         // dim chunk: dims 8j..8j+7

    int node = waveId * 8 + g;
    bool active = node < nNodes;
    int nd = active ? node : 0;

    int eStart = rowptr[nd];
    int eEnd   = active ? rowptr[nd + 1] : eStart;

    const uint4* XpV = (const uint4*)Xp;              // row stride = 8 uint4
    uint4 xr = XpV[(size_t)nd * 8 + j];               // dst row chunk (f16)

    float acc[8] = {0.f, 0.f, 0.f, 0.f, 0.f, 0.f, 0.f, 0.f};

    // prologue: batch 0 (safe index 0 for out-of-range slots)
    bool v[4]; uint4 raw[4];
#pragma unroll
    for (int u = 0; u < 4; ++u) {
        int ee = eStart + u;
        v[u] = ee < eEnd;
        int cc = col[v[u] ? ee : 0];
        raw[u] = XpV[(size_t)cc * 8 + j];
    }

    for (int e = eStart; e < eEnd; e += 4) {
        // ---- issue batch i+1 loads first (overlap with batch i compute) ----
        bool v2[4]; uint4 raw2[4];
#pragma unroll
        for (int u = 0; u < 4; ++u) {
            int ee = e + 4 + u;
            v2[u] = ee < eEnd;
            int cc = col[v2[u] ? ee : 0];
            raw2[u] = XpV[(size_t)cc * 8 + j];
        }
        // ---- consume batch i ----
        float p[4];
#pragma unroll
        for (int u = 0; u < 4; ++u) p[u] = dot8_f16(xr, raw[u], 0.f);
#pragma unroll
        for (int off = 1; off < 8; off <<= 1)
#pragma unroll
            for (int u = 0; u < 4; ++u) p[u] += __shfl_xor(p[u], off, 64);
#pragma unroll
        for (int u = 0; u < 4; ++u) {
            float s = v[u] ? p[u] : 0.f;                 // attn deferred to epilogue
            float xf[8]; h8_to_f32(raw[u], xf);
#pragma unroll
            for (int q = 0; q < 8; ++q) acc[q] = fmaf(s, xf[q], acc[q]);
        }
        // ---- rotate ----
#pragma unroll
        for (int u = 0; u < 4; ++u) { v[u] = v2[u]; raw[u] = raw2[u]; }
    }

    if (active) {
        float attn = attn_w[0];
        float4* o = (float4*)(out + (size_t)node * D + 8 * j);
        o[0] = make_float4(attn * acc[0], attn * acc[1], attn * acc[2], attn * acc[3]);
        o[1] = make_float4(attn * acc[4], attn * acc[5], attn * acc[6], attn * acc[7]);
    }
}

extern "C" void kernel_launch(void* const* d_in, const int* in_sizes, int n_in,
                              void* d_out, int out_size, void* d_ws, size_t ws_size,
                              hipStream_t stream) {
    const float* X    = (const float*)d_in[0];
    const float* W    = (const float*)d_in[1];
    const float* attn = (const float*)d_in[2];
    const int*   row  = (const int*)d_in[3];
    const int*   col  = (const int*)d_in[4];
    float* out = (float*)d_out;

    int nNodes = in_sizes[0] / D;
    int nEdges = in_sizes[3];

    // workspace layout: Xp_f16 [nNodes*D] | rowptr [nNodes+1]
    __half* Xp  = (__half*)d_ws;
    int* rowptr = (int*)((char*)d_ws + (size_t)nNodes * D * sizeof(__half));

    int gemmBlocks = 1024;
    int rpBlocks   = (nEdges + 255) / 256;
    prep_kernel<<<gemmBlocks + rpBlocks, 256, 0, stream>>>(X, W, row, Xp, rowptr,
                                                           nNodes, nEdges, gemmBlocks);

    int waves = (nNodes + 7) / 8;                        // 8 nodes per wave
    fused_kernel<<<(waves + 3) / 4, 256, 0, stream>>>(Xp, rowptr, col, attn, out, nNodes);
}